// Round 1
// baseline (116.990 us; speedup 1.0000x reference)
//
#include <hip/hip_runtime.h>
#include <hip/hip_bf16.h>

// QLoRA fwd: y = x @ (NF4dequant(codes,absmax) + adapter)^T
// x [1048576, 64] f32; W combined [64,64]; y [1048576, 64] f32.
// Memory-bound: 268MB read + 268MB write -> ~85us floor @6.3TB/s.
// Strategy: precompute combined W in bf16 (8KB, in d_ws), then MFMA
// 16x16x32_bf16 GEMM with W as A-operand (D comes out [out x token],
// so each lane's 4 acc regs = 4 consecutive outputs -> float4 stores).

#define IN_F 64
#define OUT_F 64
#define N_TOKENS 1048576

typedef __attribute__((ext_vector_type(8))) short bf16x8;   // 8 bf16 (4 VGPRs)
typedef __attribute__((ext_vector_type(4))) float f32x4;    // 4 f32 acc

__device__ __constant__ float NF4_CODE_D[16] = {
    -1.0f, -0.6961928009986877f, -0.5250730514526367f, -0.39491748809814453f,
    -0.28444138169288635f, -0.18477343022823334f, -0.09105003625154495f, 0.0f,
    0.07958029955625534f, 0.16093020141124725f, 0.24611230194568634f,
    0.33791524171829224f, 0.44070982933044434f, 0.5626170039176941f,
    0.7229568362236023f, 1.0f};

__device__ __forceinline__ unsigned short f32_to_bf16_rne(float f) {
    union { float f; unsigned int u; } v; v.f = f;
    unsigned int b = v.u + 0x7fffu + ((v.u >> 16) & 1u);  // round-nearest-even
    return (unsigned short)(b >> 16);
}

// --- Kernel 1: combined weight dequant, 4096 elements total ---
// BLOCKSIZE==IN_F==64 => NF4 block index b == output row o.
__global__ void dequant_weight_kernel(const int* __restrict__ codes,
                                      const float* __restrict__ absmax,
                                      const float* __restrict__ adapter,
                                      unsigned short* __restrict__ wbf) {
    int e = blockIdx.x * blockDim.x + threadIdx.x;
    if (e < OUT_F * IN_F) {
        int o = e >> 6;
        float w = NF4_CODE_D[codes[e]] * absmax[o] + adapter[e];
        wbf[e] = f32_to_bf16_rne(w);
    }
}

// --- Kernel 2: tall-skinny GEMM via MFMA 16x16x32 bf16 ---
// Per wave, per strip of 16 tokens:
//   A-frag (weights, cached in regs): lane l holds W[j*16 + (l&15)][s*32 + (l>>4)*8 + 0..7]
//   B-frag (x):                        lane l holds x[t0 + (l&15)][s*32 + (l>>4)*8 + 0..7]
//   D[o][t]: lane l -> token t0+(l&15), outs j*16 + (l>>4)*4 + r  (r = reg idx)
__global__ __launch_bounds__(256) void qlora_gemm_kernel(
    const float* __restrict__ x,
    const unsigned short* __restrict__ wbf,
    float* __restrict__ y,
    int nstrips, int total_waves) {

    const int lane  = threadIdx.x & 63;
    const int wave  = blockIdx.x * (blockDim.x >> 6) + (threadIdx.x >> 6);
    const int row16 = lane & 15;    // A: out row within tile / B: token within strip
    const int kgrp  = lane >> 4;    // 0..3, k sub-group

    // Load the 8 weight fragments once (8KB total, L2-resident).
    bf16x8 afrag[4][2];
#pragma unroll
    for (int j = 0; j < 4; ++j)
#pragma unroll
        for (int s = 0; s < 2; ++s) {
            const unsigned short* p = wbf + (j * 16 + row16) * 64 + s * 32 + kgrp * 8;
            afrag[j][s] = *(const bf16x8*)p;
        }

    for (int strip = wave; strip < nstrips; strip += total_waves) {
        const long t0 = (long)strip * 16;
        const float* xp = x + (t0 + row16) * 64 + kgrp * 8;
        float4 f0 = *(const float4*)(xp);        // k: kgrp*8 + 0..3   (s=0)
        float4 f1 = *(const float4*)(xp + 4);    // k: kgrp*8 + 4..7   (s=0)
        float4 f2 = *(const float4*)(xp + 32);   // s=1
        float4 f3 = *(const float4*)(xp + 36);   // s=1

        bf16x8 b0, b1;
        b0[0] = (short)f32_to_bf16_rne(f0.x); b0[1] = (short)f32_to_bf16_rne(f0.y);
        b0[2] = (short)f32_to_bf16_rne(f0.z); b0[3] = (short)f32_to_bf16_rne(f0.w);
        b0[4] = (short)f32_to_bf16_rne(f1.x); b0[5] = (short)f32_to_bf16_rne(f1.y);
        b0[6] = (short)f32_to_bf16_rne(f1.z); b0[7] = (short)f32_to_bf16_rne(f1.w);
        b1[0] = (short)f32_to_bf16_rne(f2.x); b1[1] = (short)f32_to_bf16_rne(f2.y);
        b1[2] = (short)f32_to_bf16_rne(f2.z); b1[3] = (short)f32_to_bf16_rne(f2.w);
        b1[4] = (short)f32_to_bf16_rne(f3.x); b1[5] = (short)f32_to_bf16_rne(f3.y);
        b1[6] = (short)f32_to_bf16_rne(f3.z); b1[7] = (short)f32_to_bf16_rne(f3.w);

        f32x4 acc[4];
#pragma unroll
        for (int j = 0; j < 4; ++j) {
            f32x4 c = {0.f, 0.f, 0.f, 0.f};
            c = __builtin_amdgcn_mfma_f32_16x16x32_bf16(afrag[j][0], b0, c, 0, 0, 0);
            c = __builtin_amdgcn_mfma_f32_16x16x32_bf16(afrag[j][1], b1, c, 0, 0, 0);
            acc[j] = c;
        }

        // lane l: token t0+row16, outs j*16 + kgrp*4 + {0..3} -> float4 store
        float* yp = y + (t0 + row16) * 64 + kgrp * 4;
#pragma unroll
        for (int j = 0; j < 4; ++j) {
            float4 v; v.x = acc[j][0]; v.y = acc[j][1]; v.z = acc[j][2]; v.w = acc[j][3];
            *(float4*)(yp + j * 16) = v;
        }
    }
}

extern "C" void kernel_launch(void* const* d_in, const int* in_sizes, int n_in,
                              void* d_out, int out_size, void* d_ws, size_t ws_size,
                              hipStream_t stream) {
    const float* x       = (const float*)d_in[0];
    const int*   codes   = (const int*)d_in[1];
    const float* absmax  = (const float*)d_in[2];
    const float* adapter = (const float*)d_in[3];
    float* y = (float*)d_out;
    unsigned short* wbf = (unsigned short*)d_ws;  // 64*64 bf16 = 8KB scratch

    dequant_weight_kernel<<<16, 256, 0, stream>>>(codes, absmax, adapter, wbf);

    const int threads = 256;                 // 4 waves/block
    const int blocks  = 2048;                // 8192 waves, 8 strips/wave
    const int total_waves = blocks * (threads / 64);
    const int nstrips = N_TOKENS / 16;       // 65536
    qlora_gemm_kernel<<<blocks, threads, 0, stream>>>(x, wbf, y, nstrips, total_waves);
}